// Round 6
// baseline (469.953 us; speedup 1.0000x reference)
//
#include <hip/hip_runtime.h>

// EdgeGAT on MI355X — round 6: fused sort (spin-barrier), leaner node loop, GEMM A-reuse.
//
//   memset: counts[N] + arrive[2] = 0
//   prep: cast nfeats->bf16 | BcatT bf16 [768][256] | wsum | dst histogram
//   sort_kernel (ONE launch, NB<=256 blocks co-resident, device-scope spin barriers):
//       block-local scan -> publish bsum -> barrier -> cross-block prefix ->
//       rowptr/cursor -> barrier -> grid-stride scatter -> epair (+2 sentinels)
//   gemm: 128x128 tile, inner loop over 3 col-blocks (A re-fetch 6x -> 2x),
//       global_load_lds(16B) staging, 16x16x32 bf16 MFMA
//   node_fused: per dst node (1 wave), single pass, sentinel-padded straight-line
//       loop, max(x,0.2x) leaky, paired-float math.

typedef unsigned short ushort_t;
typedef __attribute__((ext_vector_type(8))) short frag_t;     // 8 bf16 (4 VGPRs)
typedef __attribute__((ext_vector_type(4))) float f32x4;
typedef unsigned long long u64_t;

__device__ __forceinline__ ushort_t f2bf(float f) {
    unsigned u = __float_as_uint(f);
    unsigned r = u + 0x7fffu + ((u >> 16) & 1u);   // round-to-nearest-even
    return (ushort_t)(r >> 16);
}
__device__ __forceinline__ float2 bfx2(unsigned u) {   // two packed bf16 -> float2
    float2 f;
    f.x = __uint_as_float(u << 16);
    f.y = __uint_as_float(u & 0xffff0000u);
    return f;
}

// async 16B global->LDS
__device__ __forceinline__ void async_load16(const void* g, void* l) {
    __builtin_amdgcn_global_load_lds(
        (const __attribute__((address_space(1))) unsigned int*)g,
        (__attribute__((address_space(3))) unsigned int*)(unsigned int)(uintptr_t)l,
        16, 0, 0);
}

// ---- fused prep: cast | bcatT | wsum | count --------------------------------
__global__ __launch_bounds__(256) void prep_kernel(
    const float* __restrict__ nfeats, const float* __restrict__ Wni,
    const float* __restrict__ Wnj, const float* __restrict__ Wnode,
    const float* __restrict__ Wfij, const int* __restrict__ dst,
    ushort_t* __restrict__ Abf, ushort_t* __restrict__ BcatT,
    float* __restrict__ wsum, int* __restrict__ counts,
    int castB, int countB, int E) {
    int b = blockIdx.x;
    int t = threadIdx.x;
    if (b < castB) {                       // cast nfeats: 4 floats/thread
        int i = b * 256 + t;
        float4 v = *(const float4*)(nfeats + (size_t)i * 4);
        ushort4 o;
        o.x = f2bf(v.x); o.y = f2bf(v.y); o.z = f2bf(v.z); o.w = f2bf(v.w);
        *(ushort4*)(Abf + (size_t)i * 4) = o;
    } else if (b < castB + 768) {          // BcatT[j][k]
        int j = b - castB;
        int seg = j >> 8;
        const float* W = (seg == 0) ? Wni : (seg == 1) ? Wnj : Wnode;
        BcatT[(size_t)j * 256 + t] = f2bf(W[(size_t)t * 256 + (j & 255)]);
    } else if (b < castB + 768 + countB) { // dst histogram
        int i = (b - castB - 768) * 256 + t;
        if (i < E) atomicAdd(&counts[dst[i]], 1);
    } else {                               // wsum
        float s = 0.f;
#pragma unroll
        for (int k = 0; k < 32; ++k) s += Wfij[k * 256 + t];
        wsum[t] = s;
    }
}

// ---- one-launch counting sort: scan + scatter with in-kernel barriers -------
// Requires NB <= 256 blocks (all co-resident on 256 CUs; stream is otherwise idle).
__global__ __launch_bounds__(256) void sort_kernel(
    const int* __restrict__ counts, const int* __restrict__ src,
    const int* __restrict__ dst, const float* __restrict__ reward,
    int* __restrict__ bsum, int* __restrict__ rowptr, int* __restrict__ cursor,
    u64_t* __restrict__ epair, int* __restrict__ arrive, int N, int E, int NB) {
    __shared__ int sm[256];
    const int b = blockIdx.x, t = threadIdx.x;
    const int i = b * 256 + t;

    // phase 1: block-local inclusive scan of counts
    int c = (i < N) ? counts[i] : 0;
    sm[t] = c;
    __syncthreads();
    for (int off = 1; off < 256; off <<= 1) {
        int v = (t >= off) ? sm[t - off] : 0;
        __syncthreads();
        sm[t] += v;
        __syncthreads();
    }
    int incl = sm[t];
    int total = sm[255];
    if (t == 0) {
        bsum[b] = total;
        __threadfence();
        atomicAdd(&arrive[0], 1);
        while (__hip_atomic_load(&arrive[0], __ATOMIC_ACQUIRE,
                                 __HIP_MEMORY_SCOPE_AGENT) < NB) {}
    }
    __syncthreads();

    // phase 2: prefix over blocks (tree-reduce bsum[0..b-1])
    sm[t] = (t < b) ? bsum[t] : 0;
    __syncthreads();
#pragma unroll
    for (int off = 128; off; off >>= 1) {
        if (t < off) sm[t] += sm[t + off];
        __syncthreads();
    }
    int prefix = sm[0];
    int ex = prefix + incl - c;            // exclusive scan value
    if (i < N) { rowptr[i] = ex; cursor[i] = ex; }
    if (i == 0) {
        rowptr[N] = E;
        epair[E] = 0; epair[E + 1] = 0;    // sentinels for node_fused pipeline
    }
    __threadfence();
    if (t == 0) {
        atomicAdd(&arrive[1], 1);
        while (__hip_atomic_load(&arrive[1], __ATOMIC_ACQUIRE,
                                 __HIP_MEMORY_SCOPE_AGENT) < NB) {}
    }
    __syncthreads();

    // phase 3: grid-stride scatter
    for (int idx = i; idx < E; idx += NB * 256) {
        int d = dst[idx];
        int pos = atomicAdd(&cursor[d], 1);
        epair[pos] = ((u64_t)__float_as_uint(reward[idx]) << 32) | (unsigned)src[idx];
    }
}

// ---- MFMA GEMM 128x128, inner 3-col-block loop, global_load_lds staging -----
__global__ __launch_bounds__(256) void gemm_mfma(
    const ushort_t* __restrict__ A, const ushort_t* __restrict__ BT,
    const float* __restrict__ bias, ushort_t* __restrict__ fnih,
    ushort_t* __restrict__ fnj, int N) {
    __shared__ ushort_t As[128][32];
    __shared__ ushort_t Bs[128][32];

    const int tid = threadIdx.x;
    const int wave = tid >> 6, lane = tid & 63;
    const int quad = lane >> 4, l16 = lane & 15;
    const int wr = wave & 1, wc = wave >> 1;
    const int row0 = blockIdx.x * 128;
    const int Nm1 = N - 1;

    for (int cblk = 0; cblk < 3; ++cblk) {
        const int col0 = blockIdx.y * 384 + cblk * 128;   // 0..640

        f32x4 acc[4][4] = {};

        for (int k0 = 0; k0 < 256; k0 += 32) {
            __syncthreads();
#pragma unroll
            for (int j = 0; j < 2; ++j) {
                int r = wave * 32 + j * 16 + (lane >> 2);
                int grow = row0 + r; if (grow > Nm1) grow = Nm1;
                async_load16(A + (size_t)grow * 256 + k0 + (lane & 3) * 8,
                             &As[wave * 32 + j * 16][0]);
            }
#pragma unroll
            for (int j = 0; j < 2; ++j) {
                int r = wave * 32 + j * 16 + (lane >> 2);
                async_load16(BT + (size_t)(col0 + r) * 256 + k0 + (lane & 3) * 8,
                             &Bs[wave * 32 + j * 16][0]);
            }
            __syncthreads();

            frag_t af[4], bfr[4];
#pragma unroll
            for (int i = 0; i < 4; ++i)
                af[i] = *(const frag_t*)&As[wr * 64 + i * 16 + l16][quad * 8];
#pragma unroll
            for (int j = 0; j < 4; ++j)
                bfr[j] = *(const frag_t*)&Bs[wc * 64 + j * 16 + l16][quad * 8];

#pragma unroll
            for (int i = 0; i < 4; ++i)
#pragma unroll
                for (int j = 0; j < 4; ++j)
                    acc[i][j] = __builtin_amdgcn_mfma_f32_16x16x32_bf16(af[i], bfr[j], acc[i][j], 0, 0, 0);
        }

#pragma unroll
        for (int i = 0; i < 4; ++i) {
#pragma unroll
            for (int j = 0; j < 4; ++j) {
#pragma unroll
                for (int r = 0; r < 4; ++r) {
                    int row = row0 + wr * 64 + i * 16 + quad * 4 + r;
                    if (row >= N) continue;
                    int col = col0 + wc * 64 + j * 16 + l16;
                    float v = acc[i][j][r];
                    if (col < 256) {
                        fnih[(size_t)row * 512 + col] = f2bf(v + bias[col]);
                    } else if (col < 512) {
                        fnj[(size_t)row * 256 + (col - 256)] = f2bf(v);
                    } else {
                        int c2 = col - 512;   // h = c2>>6, o = c2&63 -> o-major
                        fnih[(size_t)row * 512 + 256 + (c2 & 63) * 4 + (c2 >> 6)] = f2bf(v);
                    }
                }
            }
        }
    }
}

// ---- fused per-node edge phase (single pass, straight-line pipelined) -------
__global__ __launch_bounds__(256) void node_fused(
    const ushort_t* __restrict__ fnih, const ushort_t* __restrict__ fnj,
    const int* __restrict__ rowptr, const u64_t* __restrict__ epair,
    const float* __restrict__ wsum, const float* __restrict__ attn,
    float* __restrict__ out, int N) {
    int node = (int)((blockIdx.x * (size_t)blockDim.x + threadIdx.x) >> 6);
    int lane = threadIdx.x & 63;
    if (node >= N) return;

    int base = rowptr[node], end = rowptr[node + 1];
    if (base >= end) { out[(size_t)node * 64 + lane] = 0.f; return; }
    int j0 = lane * 4;

    float4 wsv = *(const float4*)(wsum + j0);
    float4 atv = *(const float4*)(attn + j0);
    uint2 nju = *(const uint2*)(fnj + (size_t)node * 256 + j0);
    float2 nj01 = bfx2(nju.x), nj23 = bfx2(nju.y);

    float a0 = 0.f, a1 = 0.f, a2 = 0.f, a3 = 0.f, dsum = 0.f;

    u64_t p0 = epair[base];
    u64_t p1 = epair[base + 1];                       // sentinel-safe
    const ushort_t* fp = fnih + (size_t)(unsigned)p0 * 512 + j0;
    uint2 niu = *(const uint2*)fp;
    uint2 hvu = *(const uint2*)(fp + 256);

    for (int e = base; e < end; ++e) {
        u64_t pn = epair[e + 2];                      // sentinel-safe
        const ushort_t* fq = fnih + (size_t)(unsigned)p1 * 512 + j0;
        uint2 niu_n = *(const uint2*)fq;
        uint2 hvu_n = *(const uint2*)(fq + 256);

        float r = __uint_as_float((unsigned)(p0 >> 32));
        float2 b01 = bfx2(niu.x), b23 = bfx2(niu.y);
        float x0 = fmaf(r, wsv.x, nj01.x) + b01.x;
        float x1 = fmaf(r, wsv.y, nj01.y) + b01.y;
        float x2 = fmaf(r, wsv.z, nj23.x) + b23.x;
        float x3 = fmaf(r, wsv.w, nj23.y) + b23.y;
        x0 = fmaxf(x0, 0.2f * x0);                    // leaky_relu
        x1 = fmaxf(x1, 0.2f * x1);
        x2 = fmaxf(x2, 0.2f * x2);
        x3 = fmaxf(x3, 0.2f * x3);
        float acc = atv.x * x0 + atv.y * x1 + atv.z * x2 + atv.w * x3;
        acc += __shfl_xor(acc, 1, 64);
        acc += __shfl_xor(acc, 2, 64);
        acc += __shfl_xor(acc, 4, 64);
        acc += __shfl_xor(acc, 8, 64);
        float eh = __expf(acc);
        dsum += eh;

        float e0 = __shfl(eh, 0, 64);
        float e1 = __shfl(eh, 16, 64);
        float e2 = __shfl(eh, 32, 64);
        float e3 = __shfl(eh, 48, 64);
        float2 h01 = bfx2(hvu.x), h23 = bfx2(hvu.y);
        a0 = fmaf(e0, h01.x, a0);
        a1 = fmaf(e1, h01.y, a1);
        a2 = fmaf(e2, h23.x, a2);
        a3 = fmaf(e3, h23.y, a3);

        p0 = p1; p1 = pn; niu = niu_n; hvu = hvu_n;
    }

    float d0 = __shfl(dsum, 0, 64);
    float d1 = __shfl(dsum, 16, 64);
    float d2 = __shfl(dsum, 32, 64);
    float d3 = __shfl(dsum, 48, 64);
    float v = 0.25f * (__fdividef(a0, d0) + __fdividef(a1, d1) +
                       __fdividef(a2, d2) + __fdividef(a3, d3));
    out[(size_t)node * 64 + lane] = fmaxf(v, 0.f);
}

// ---- launch -----------------------------------------------------------------

extern "C" void kernel_launch(void* const* d_in, const int* in_sizes, int n_in,
                              void* d_out, int out_size, void* d_ws, size_t ws_size,
                              hipStream_t stream) {
    const float* nfeats = (const float*)d_in[0];
    const float* reward = (const float*)d_in[1];
    const int* src = (const int*)d_in[2];
    const int* dst = (const int*)d_in[3];
    const float* Wni = (const float*)d_in[4];
    const float* Wnj = (const float*)d_in[5];
    const float* Wfij = (const float*)d_in[6];
    const float* Wnode = (const float*)d_in[7];
    const float* bias = (const float*)d_in[8];
    const float* attn = (const float*)d_in[9];
    float* out = (float*)d_out;

    const int N = in_sizes[0] / 256;
    const int E = in_sizes[1];
    const int NB = (N + 255) / 256;       // must be <= 256 (N <= 65536)
    const int castB = (N * 64 + 255) / 256;
    const int countB = (E + 255) / 256;

    char* p = (char*)d_ws;
    auto alloc = [&](size_t bytes) { char* r = p; p += (bytes + 63) & ~63ull; return r; };
    u64_t* epair = (u64_t*)alloc((size_t)(E + 2) * sizeof(u64_t));
    float* wsum = (float*)alloc(256 * sizeof(float));
    int* counts = (int*)alloc((size_t)(N + 2) * sizeof(int));  // +2: arrive ctrs
    int* arrive = counts + N;
    int* bsum = (int*)alloc(256 * sizeof(int));
    int* rowptr = (int*)alloc((size_t)(N + 1) * sizeof(int));
    int* cursor = (int*)alloc((size_t)N * sizeof(int));
    ushort_t* fnih = (ushort_t*)alloc((size_t)N * 512 * sizeof(ushort_t));
    ushort_t* fnj = (ushort_t*)alloc((size_t)N * 256 * sizeof(ushort_t));
    ushort_t* Abf = (ushort_t*)alloc((size_t)N * 256 * sizeof(ushort_t));
    ushort_t* BcatT = (ushort_t*)alloc((size_t)768 * 256 * sizeof(ushort_t));

    hipMemsetAsync(counts, 0, (size_t)(N + 2) * sizeof(int), stream);

    prep_kernel<<<castB + 768 + countB + 1, 256, 0, stream>>>(
        nfeats, Wni, Wnj, Wnode, Wfij, dst, Abf, BcatT, wsum, counts,
        castB, countB, E);

    sort_kernel<<<NB, 256, 0, stream>>>(counts, src, dst, reward, bsum, rowptr,
                                        cursor, epair, arrive, N, E, NB);

    dim3 g1((N + 127) / 128, 2);
    gemm_mfma<<<g1, 256, 0, stream>>>(Abf, BcatT, bias, fnih, fnj, N);

    node_fused<<<(N + 3) / 4, 256, 0, stream>>>(fnih, fnj, rowptr, epair,
                                                wsum, attn, out, N);
}

// Round 8
// 388.071 us; speedup vs baseline: 1.2110x; 1.2110x over previous
//
#include <hip/hip_runtime.h>

// EdgeGAT on MI355X — round 8: r5 pipeline (proven) + node_fused VALU diet.
//
//   prep: cast nfeats->bf16 | BcatT bf16 [768][256] | wsum | dst histogram
//   scan1/scan2/scan3 + scatter: counting sort by dst -> rowptr + epair (8B)
//   gemm: r5-exact 128x128 tile, global_load_lds(16B) staging, 16x16x32 bf16
//         MFMA. Epilogue layout change only: fnih row = per-lane 16B chunks
//         [ni(4 dims) | hv(4 heads)] so node_fused does ONE ushort8 gather.
//   node_fused: r5 loop structure (conditional 1-edge-ahead prefetch) with
//         scalar (readfirstlane) src base, single 16B gather, fmax leaky.

typedef unsigned short ushort_t;
typedef __attribute__((ext_vector_type(8))) short frag_t;     // 8 bf16 (4 VGPRs)
typedef __attribute__((ext_vector_type(4))) float f32x4;
typedef unsigned long long u64_t;

__device__ __forceinline__ ushort_t f2bf(float f) {
    unsigned u = __float_as_uint(f);
    unsigned r = u + 0x7fffu + ((u >> 16) & 1u);   // round-to-nearest-even
    return (ushort_t)(r >> 16);
}
__device__ __forceinline__ float bf2f(ushort_t v) {
    return __uint_as_float(((unsigned)v) << 16);
}
__device__ __forceinline__ float2 bfx2(unsigned u) {   // packed [lo,hi] bf16 -> float2
    float2 f;
    f.x = __uint_as_float(u << 16);
    f.y = __uint_as_float(u & 0xffff0000u);
    return f;
}

// async 16B global->LDS
__device__ __forceinline__ void async_load16(const void* g, void* l) {
    __builtin_amdgcn_global_load_lds(
        (const __attribute__((address_space(1))) unsigned int*)g,
        (__attribute__((address_space(3))) unsigned int*)(unsigned int)(uintptr_t)l,
        16, 0, 0);
}

// ---- fused prep: cast | bcatT | wsum | count --------------------------------
__global__ __launch_bounds__(256) void prep_kernel(
    const float* __restrict__ nfeats, const float* __restrict__ Wni,
    const float* __restrict__ Wnj, const float* __restrict__ Wnode,
    const float* __restrict__ Wfij, const int* __restrict__ dst,
    ushort_t* __restrict__ Abf, ushort_t* __restrict__ BcatT,
    float* __restrict__ wsum, int* __restrict__ counts,
    int castB, int countB, int E) {
    int b = blockIdx.x;
    int t = threadIdx.x;
    if (b < castB) {                       // cast nfeats: 4 floats/thread
        int i = b * 256 + t;
        float4 v = *(const float4*)(nfeats + (size_t)i * 4);
        ushort4 o;
        o.x = f2bf(v.x); o.y = f2bf(v.y); o.z = f2bf(v.z); o.w = f2bf(v.w);
        *(ushort4*)(Abf + (size_t)i * 4) = o;
    } else if (b < castB + 768) {          // BcatT[j][k]
        int j = b - castB;
        int seg = j >> 8;
        const float* W = (seg == 0) ? Wni : (seg == 1) ? Wnj : Wnode;
        BcatT[(size_t)j * 256 + t] = f2bf(W[(size_t)t * 256 + (j & 255)]);
    } else if (b < castB + 768 + countB) { // dst histogram
        int i = (b - castB - 768) * 256 + t;
        if (i < E) atomicAdd(&counts[dst[i]], 1);
    } else {                               // wsum
        float s = 0.f;
#pragma unroll
        for (int k = 0; k < 32; ++k) s += Wfij[k * 256 + t];
        wsum[t] = s;
    }
}

// ---- MFMA GEMM 128x128, global_load_lds staging (r5-exact structure) --------
__global__ __launch_bounds__(256) void gemm_mfma(
    const ushort_t* __restrict__ A, const ushort_t* __restrict__ BT,
    const float* __restrict__ bias, ushort_t* __restrict__ fnih,
    ushort_t* __restrict__ fnj, int N) {
    __shared__ ushort_t As[128][32];   // unpadded: global_load_lds dest is lane-linear
    __shared__ ushort_t Bs[128][32];

    const int tid = threadIdx.x;
    const int wave = tid >> 6, lane = tid & 63;
    const int quad = lane >> 4, l16 = lane & 15;
    const int wr = wave & 1, wc = wave >> 1;
    const int row0 = blockIdx.x * 128;
    const int col0 = blockIdx.y * 128;         // 0..640
    const int Nm1 = N - 1;

    f32x4 acc[4][4] = {};

    for (int k0 = 0; k0 < 256; k0 += 32) {
        if (k0) __syncthreads();
#pragma unroll
        for (int j = 0; j < 2; ++j) {
            int r = wave * 32 + j * 16 + (lane >> 2);
            int grow = row0 + r; if (grow > Nm1) grow = Nm1;   // clamp, discarded later
            async_load16(A + (size_t)grow * 256 + k0 + (lane & 3) * 8,
                         &As[wave * 32 + j * 16][0]);
        }
#pragma unroll
        for (int j = 0; j < 2; ++j) {
            int r = wave * 32 + j * 16 + (lane >> 2);
            async_load16(BT + (size_t)(col0 + r) * 256 + k0 + (lane & 3) * 8,
                         &Bs[wave * 32 + j * 16][0]);
        }
        __syncthreads();

        frag_t af[4], bfr[4];
#pragma unroll
        for (int i = 0; i < 4; ++i)
            af[i] = *(const frag_t*)&As[wr * 64 + i * 16 + l16][quad * 8];
#pragma unroll
        for (int j = 0; j < 4; ++j)
            bfr[j] = *(const frag_t*)&Bs[wc * 64 + j * 16 + l16][quad * 8];

#pragma unroll
        for (int i = 0; i < 4; ++i)
#pragma unroll
            for (int j = 0; j < 4; ++j)
                acc[i][j] = __builtin_amdgcn_mfma_f32_16x16x32_bf16(af[i], bfr[j], acc[i][j], 0, 0, 0);
    }

    // epilogue: fnih interleaved row layout:
    //   ni dim c  -> offset (c>>2)*8 + (c&3)        (lane c>>2, slot 0..3)
    //   hv (h,o)  -> offset o*8 + 4 + h             (lane o,    slot 4..7)
#pragma unroll
    for (int i = 0; i < 4; ++i) {
#pragma unroll
        for (int j = 0; j < 4; ++j) {
#pragma unroll
            for (int r = 0; r < 4; ++r) {
                int row = row0 + wr * 64 + i * 16 + quad * 4 + r;
                if (row >= N) continue;
                int col = col0 + wc * 64 + j * 16 + l16;
                float v = acc[i][j][r];
                if (col < 256) {
                    fnih[(size_t)row * 512 + (col >> 2) * 8 + (col & 3)] =
                        f2bf(v + bias[col]);
                } else if (col < 512) {
                    fnj[(size_t)row * 256 + (col - 256)] = f2bf(v);
                } else {
                    int c2 = col - 512;   // h = c2>>6, o = c2&63
                    fnih[(size_t)row * 512 + (c2 & 63) * 8 + 4 + (c2 >> 6)] = f2bf(v);
                }
            }
        }
    }
}

// ---- scans ------------------------------------------------------------------

__global__ __launch_bounds__(256) void scan_block_sums(const int* __restrict__ counts,
                                                       int* __restrict__ bsum, int N) {
    __shared__ int sm[256];
    int i = blockIdx.x * 256 + threadIdx.x;
    sm[threadIdx.x] = (i < N) ? counts[i] : 0;
    __syncthreads();
#pragma unroll
    for (int off = 128; off; off >>= 1) {
        if (threadIdx.x < off) sm[threadIdx.x] += sm[threadIdx.x + off];
        __syncthreads();
    }
    if (threadIdx.x == 0) bsum[blockIdx.x] = sm[0];
}

__global__ __launch_bounds__(256) void scan_top(const int* __restrict__ bsum,
                                                int* __restrict__ bsum_ex, int NB) {
    __shared__ int sm[256];
    int t = threadIdx.x;
    sm[t] = (t < NB) ? bsum[t] : 0;
    __syncthreads();
    for (int off = 1; off < 256; off <<= 1) {
        int v = (t >= off) ? sm[t - off] : 0;
        __syncthreads();
        sm[t] += v;
        __syncthreads();
    }
    if (t < NB) bsum_ex[t] = (t == 0) ? 0 : sm[t - 1];
}

__global__ __launch_bounds__(256) void scan_final(const int* __restrict__ counts,
                                                  const int* __restrict__ bsum_ex,
                                                  int* __restrict__ rowptr,
                                                  int* __restrict__ cursor, int N, int E) {
    __shared__ int sm[256];
    int t = threadIdx.x;
    int i = blockIdx.x * 256 + t;
    sm[t] = (i < N) ? counts[i] : 0;
    __syncthreads();
    for (int off = 1; off < 256; off <<= 1) {
        int v = (t >= off) ? sm[t - off] : 0;
        __syncthreads();
        sm[t] += v;
        __syncthreads();
    }
    int ex = bsum_ex[blockIdx.x] + ((t == 0) ? 0 : sm[t - 1]);
    if (i < N) { rowptr[i] = ex; cursor[i] = ex; }
    if (i == 0) rowptr[N] = E;
}

__global__ __launch_bounds__(256) void scatter_kernel(
    const int* __restrict__ src, const int* __restrict__ dst,
    const float* __restrict__ reward, int* __restrict__ cursor,
    u64_t* __restrict__ epair, int E) {
    int i = blockIdx.x * 256 + threadIdx.x;
    if (i < E) {
        int d = dst[i];
        int pos = atomicAdd(&cursor[d], 1);
        epair[pos] = ((u64_t)__float_as_uint(reward[i]) << 32) | (unsigned)src[i];
    }
}

// ---- fused per-node edge phase (r5 structure, VALU diet) --------------------

__global__ __launch_bounds__(256) void node_fused(
    const ushort_t* __restrict__ fnih, const ushort_t* __restrict__ fnj,
    const int* __restrict__ rowptr, const u64_t* __restrict__ epair,
    const float* __restrict__ wsum, const float* __restrict__ attn,
    float* __restrict__ out, int N) {
    int node = (int)((blockIdx.x * (size_t)blockDim.x + threadIdx.x) >> 6);
    int lane = threadIdx.x & 63;
    if (node >= N) return;

    int base = rowptr[node], end = rowptr[node + 1];
    int j0 = lane * 4;
    if (base >= end) { out[(size_t)node * 64 + lane] = 0.f; return; }

    float4 ws = *(const float4*)(wsum + j0);
    float4 at = *(const float4*)(attn + j0);
    ushort4 njv = *(const ushort4*)(fnj + (size_t)node * 256 + j0);
    float nj0 = bf2f(njv.x), nj1 = bf2f(njv.y), nj2 = bf2f(njv.z), nj3 = bf2f(njv.w);

    float a0 = 0.f, a1 = 0.f, a2 = 0.f, a3 = 0.f, dsum = 0.f;
    const int lo16 = lane * 8;   // byte-chunk offset within a fnih row (shorts)

    u64_t p0 = epair[base];
    u64_t p1 = (base + 1 < end) ? epair[base + 1] : 0;
    int s0 = __builtin_amdgcn_readfirstlane((int)(unsigned)p0);
    uint4 gv = *(const uint4*)(fnih + (size_t)(unsigned)s0 * 512 + lo16);

    for (int e = base; e < end; ++e) {
        u64_t pn = (e + 2 < end) ? epair[e + 2] : 0;
        uint4 gv_n = gv;
        if (e + 1 < end) {
            int s1 = __builtin_amdgcn_readfirstlane((int)(unsigned)p1);
            gv_n = *(const uint4*)(fnih + (size_t)(unsigned)s1 * 512 + lo16);
        }

        float r = __uint_as_float(
            __builtin_amdgcn_readfirstlane((int)(unsigned)(p0 >> 32)));
        float2 b01 = bfx2(gv.x), b23 = bfx2(gv.y);
        float x0 = fmaf(r, ws.x, nj0) + b01.x;
        float x1 = fmaf(r, ws.y, nj1) + b01.y;
        float x2 = fmaf(r, ws.z, nj2) + b23.x;
        float x3 = fmaf(r, ws.w, nj3) + b23.y;
        x0 = fmaxf(x0, 0.2f * x0);                 // leaky (identical to select)
        x1 = fmaxf(x1, 0.2f * x1);
        x2 = fmaxf(x2, 0.2f * x2);
        x3 = fmaxf(x3, 0.2f * x3);
        float acc = at.x * x0 + at.y * x1 + at.z * x2 + at.w * x3;
        acc += __shfl_xor(acc, 1, 64);
        acc += __shfl_xor(acc, 2, 64);
        acc += __shfl_xor(acc, 4, 64);
        acc += __shfl_xor(acc, 8, 64);
        float eh = __expf(acc);
        dsum += eh;

        float e0 = __shfl(eh, 0, 64);
        float e1 = __shfl(eh, 16, 64);
        float e2 = __shfl(eh, 32, 64);
        float e3 = __shfl(eh, 48, 64);
        float2 h01 = bfx2(gv.z), h23 = bfx2(gv.w);
        a0 = fmaf(e0, h01.x, a0);
        a1 = fmaf(e1, h01.y, a1);
        a2 = fmaf(e2, h23.x, a2);
        a3 = fmaf(e3, h23.y, a3);

        p0 = p1; p1 = pn; gv = gv_n;
    }

    float d0 = __shfl(dsum, 0, 64);
    float d1 = __shfl(dsum, 16, 64);
    float d2 = __shfl(dsum, 32, 64);
    float d3 = __shfl(dsum, 48, 64);
    float v = 0.25f * (__fdividef(a0, d0) + __fdividef(a1, d1) +
                       __fdividef(a2, d2) + __fdividef(a3, d3));
    out[(size_t)node * 64 + lane] = fmaxf(v, 0.f);
}

// ---- launch -----------------------------------------------------------------

extern "C" void kernel_launch(void* const* d_in, const int* in_sizes, int n_in,
                              void* d_out, int out_size, void* d_ws, size_t ws_size,
                              hipStream_t stream) {
    const float* nfeats = (const float*)d_in[0];
    const float* reward = (const float*)d_in[1];
    const int* src = (const int*)d_in[2];
    const int* dst = (const int*)d_in[3];
    const float* Wni = (const float*)d_in[4];
    const float* Wnj = (const float*)d_in[5];
    const float* Wfij = (const float*)d_in[6];
    const float* Wnode = (const float*)d_in[7];
    const float* bias = (const float*)d_in[8];
    const float* attn = (const float*)d_in[9];
    float* out = (float*)d_out;

    const int N = in_sizes[0] / 256;
    const int E = in_sizes[1];
    const int NB = (N + 255) / 256;       // <= 256 (N <= 65536)
    const int castB = (N * 64 + 255) / 256;
    const int countB = (E + 255) / 256;

    char* p = (char*)d_ws;
    auto alloc = [&](size_t bytes) { char* r = p; p += (bytes + 63) & ~63ull; return r; };
    u64_t* epair = (u64_t*)alloc((size_t)E * sizeof(u64_t));
    float* wsum = (float*)alloc(256 * sizeof(float));
    int* counts = (int*)alloc((size_t)N * sizeof(int));
    int* bsum = (int*)alloc(256 * sizeof(int));
    int* bsum_ex = (int*)alloc(256 * sizeof(int));
    int* rowptr = (int*)alloc((size_t)(N + 1) * sizeof(int));
    int* cursor = (int*)alloc((size_t)N * sizeof(int));
    ushort_t* fnih = (ushort_t*)alloc((size_t)N * 512 * sizeof(ushort_t));
    ushort_t* fnj = (ushort_t*)alloc((size_t)N * 256 * sizeof(ushort_t));
    ushort_t* Abf = (ushort_t*)alloc((size_t)N * 256 * sizeof(ushort_t));
    ushort_t* BcatT = (ushort_t*)alloc((size_t)768 * 256 * sizeof(ushort_t));

    hipMemsetAsync(counts, 0, (size_t)N * sizeof(int), stream);

    prep_kernel<<<castB + 768 + countB + 1, 256, 0, stream>>>(
        nfeats, Wni, Wnj, Wnode, Wfij, dst, Abf, BcatT, wsum, counts,
        castB, countB, E);

    scan_block_sums<<<NB, 256, 0, stream>>>(counts, bsum, N);
    scan_top<<<1, 256, 0, stream>>>(bsum, bsum_ex, NB);
    scan_final<<<NB, 256, 0, stream>>>(counts, bsum_ex, rowptr, cursor, N, E);
    scatter_kernel<<<countB, 256, 0, stream>>>(src, dst, reward, cursor, epair, E);

    dim3 g1((N + 127) / 128, 6);
    gemm_mfma<<<g1, 256, 0, stream>>>(Abf, BcatT, bias, fnih, fnj, N);

    node_fused<<<(N + 3) / 4, 256, 0, stream>>>(fnih, fnj, rowptr, epair,
                                                wsum, attn, out, N);
}

// Round 9
// 381.039 us; speedup vs baseline: 1.2333x; 1.0185x over previous
//
#include <hip/hip_runtime.h>

// EdgeGAT on MI355X — round 9: double-buffered GEMM K-loop (1 barrier/step),
// scan_top folded into scan_final, grid-strided cast. node_fused = r8-exact.
//
//   prep: cast nfeats->bf16 (x4/thread) | BcatT bf16 [768][256] | wsum | dst hist
//   scan_block_sums + scan_final(self-prefix) + scatter: sort by dst
//   gemm: 128x128 tile, BK=32, DOUBLE-BUFFERED global_load_lds staging
//         (8 barriers vs 16), 16x16x32 bf16 MFMA, r8 interleaved fnih epilogue.
//   node_fused: r8-exact (121.6 us proven).

typedef unsigned short ushort_t;
typedef __attribute__((ext_vector_type(8))) short frag_t;     // 8 bf16 (4 VGPRs)
typedef __attribute__((ext_vector_type(4))) float f32x4;
typedef unsigned long long u64_t;

__device__ __forceinline__ ushort_t f2bf(float f) {
    unsigned u = __float_as_uint(f);
    unsigned r = u + 0x7fffu + ((u >> 16) & 1u);   // round-to-nearest-even
    return (ushort_t)(r >> 16);
}
__device__ __forceinline__ float bf2f(ushort_t v) {
    return __uint_as_float(((unsigned)v) << 16);
}
__device__ __forceinline__ float2 bfx2(unsigned u) {   // packed [lo,hi] bf16 -> float2
    float2 f;
    f.x = __uint_as_float(u << 16);
    f.y = __uint_as_float(u & 0xffff0000u);
    return f;
}

// async 16B global->LDS
__device__ __forceinline__ void async_load16(const void* g, void* l) {
    __builtin_amdgcn_global_load_lds(
        (const __attribute__((address_space(1))) unsigned int*)g,
        (__attribute__((address_space(3))) unsigned int*)(unsigned int)(uintptr_t)l,
        16, 0, 0);
}

// ---- fused prep: cast | bcatT | wsum | count --------------------------------
__global__ __launch_bounds__(256) void prep_kernel(
    const float* __restrict__ nfeats, const float* __restrict__ Wni,
    const float* __restrict__ Wnj, const float* __restrict__ Wnode,
    const float* __restrict__ Wfij, const int* __restrict__ dst,
    ushort_t* __restrict__ Abf, ushort_t* __restrict__ BcatT,
    float* __restrict__ wsum, int* __restrict__ counts,
    int castB, int countB, int total4, int E) {
    int b = blockIdx.x;
    int t = threadIdx.x;
    if (b < castB) {                       // cast nfeats: 4x float4 per thread
#pragma unroll
        for (int cc = 0; cc < 4; ++cc) {
            int i = (b * 4 + cc) * 256 + t;
            if (i >= total4) break;
            float4 v = *(const float4*)(nfeats + (size_t)i * 4);
            ushort4 o;
            o.x = f2bf(v.x); o.y = f2bf(v.y); o.z = f2bf(v.z); o.w = f2bf(v.w);
            *(ushort4*)(Abf + (size_t)i * 4) = o;
        }
    } else if (b < castB + 768) {          // BcatT[j][k]
        int j = b - castB;
        int seg = j >> 8;
        const float* W = (seg == 0) ? Wni : (seg == 1) ? Wnj : Wnode;
        BcatT[(size_t)j * 256 + t] = f2bf(W[(size_t)t * 256 + (j & 255)]);
    } else if (b < castB + 768 + countB) { // dst histogram
        int i = (b - castB - 768) * 256 + t;
        if (i < E) atomicAdd(&counts[dst[i]], 1);
    } else {                               // wsum
        float s = 0.f;
#pragma unroll
        for (int k = 0; k < 32; ++k) s += Wfij[k * 256 + t];
        wsum[t] = s;
    }
}

// ---- MFMA GEMM 128x128, double-buffered global_load_lds staging -------------
__global__ __launch_bounds__(256) void gemm_mfma(
    const ushort_t* __restrict__ A, const ushort_t* __restrict__ BT,
    const float* __restrict__ bias, ushort_t* __restrict__ fnih,
    ushort_t* __restrict__ fnj, int N) {
    __shared__ ushort_t As[2][128][32];
    __shared__ ushort_t Bs[2][128][32];

    const int tid = threadIdx.x;
    const int wave = tid >> 6, lane = tid & 63;
    const int quad = lane >> 4, l16 = lane & 15;
    const int wr = wave & 1, wc = wave >> 1;
    const int row0 = blockIdx.x * 128;
    const int col0 = blockIdx.y * 128;         // 0..640
    const int Nm1 = N - 1;
    const int srow = lane >> 2;                // staging: lane -> row within 16
    const int skof = (lane & 3) * 8;           // staging: lane -> k offset

    f32x4 acc[4][4] = {};

    // prologue: stage buffer 0 for k0=0
#pragma unroll
    for (int j = 0; j < 2; ++j) {
        int r = wave * 32 + j * 16 + srow;
        int grow = row0 + r; if (grow > Nm1) grow = Nm1;
        async_load16(A + (size_t)grow * 256 + skof, &As[0][wave * 32 + j * 16][0]);
        async_load16(BT + (size_t)(col0 + r) * 256 + skof, &Bs[0][wave * 32 + j * 16][0]);
    }

    for (int it = 0; it < 8; ++it) {
        const int cur = it & 1;
        __syncthreads();                   // drains async into buf[cur]; protects re-stage
        if (it < 7) {
            const int k1 = (it + 1) * 32;
#pragma unroll
            for (int j = 0; j < 2; ++j) {
                int r = wave * 32 + j * 16 + srow;
                int grow = row0 + r; if (grow > Nm1) grow = Nm1;
                async_load16(A + (size_t)grow * 256 + k1 + skof,
                             &As[1 - cur][wave * 32 + j * 16][0]);
                async_load16(BT + (size_t)(col0 + r) * 256 + k1 + skof,
                             &Bs[1 - cur][wave * 32 + j * 16][0]);
            }
        }

        frag_t af[4], bfr[4];
#pragma unroll
        for (int i = 0; i < 4; ++i)
            af[i] = *(const frag_t*)&As[cur][wr * 64 + i * 16 + l16][quad * 8];
#pragma unroll
        for (int j = 0; j < 4; ++j)
            bfr[j] = *(const frag_t*)&Bs[cur][wc * 64 + j * 16 + l16][quad * 8];

#pragma unroll
        for (int i = 0; i < 4; ++i)
#pragma unroll
            for (int j = 0; j < 4; ++j)
                acc[i][j] = __builtin_amdgcn_mfma_f32_16x16x32_bf16(af[i], bfr[j], acc[i][j], 0, 0, 0);
    }

    // epilogue (r8): fnih interleaved row layout:
    //   ni dim c  -> offset (c>>2)*8 + (c&3)    (lane c>>2, slot 0..3)
    //   hv (h,o)  -> offset o*8 + 4 + h         (lane o,    slot 4..7)
#pragma unroll
    for (int i = 0; i < 4; ++i) {
#pragma unroll
        for (int j = 0; j < 4; ++j) {
#pragma unroll
            for (int r = 0; r < 4; ++r) {
                int row = row0 + wr * 64 + i * 16 + quad * 4 + r;
                if (row >= N) continue;
                int col = col0 + wc * 64 + j * 16 + l16;
                float v = acc[i][j][r];
                if (col < 256) {
                    fnih[(size_t)row * 512 + (col >> 2) * 8 + (col & 3)] =
                        f2bf(v + bias[col]);
                } else if (col < 512) {
                    fnj[(size_t)row * 256 + (col - 256)] = f2bf(v);
                } else {
                    int c2 = col - 512;   // h = c2>>6, o = c2&63
                    fnih[(size_t)row * 512 + (c2 & 63) * 8 + 4 + (c2 >> 6)] = f2bf(v);
                }
            }
        }
    }
}

// ---- scans ------------------------------------------------------------------

__global__ __launch_bounds__(256) void scan_block_sums(const int* __restrict__ counts,
                                                       int* __restrict__ bsum, int N) {
    __shared__ int sm[256];
    int i = blockIdx.x * 256 + threadIdx.x;
    sm[threadIdx.x] = (i < N) ? counts[i] : 0;
    __syncthreads();
#pragma unroll
    for (int off = 128; off; off >>= 1) {
        if (threadIdx.x < off) sm[threadIdx.x] += sm[threadIdx.x + off];
        __syncthreads();
    }
    if (threadIdx.x == 0) bsum[blockIdx.x] = sm[0];
}

// self-prefix: each block tree-reduces bsum[0..b-1] (NB<=256), then local scan.
__global__ __launch_bounds__(256) void scan_final(const int* __restrict__ counts,
                                                  const int* __restrict__ bsum,
                                                  int* __restrict__ rowptr,
                                                  int* __restrict__ cursor, int N, int E) {
    __shared__ int sm[256];
    __shared__ int smp[256];
    int t = threadIdx.x;
    int b = blockIdx.x;
    int i = b * 256 + t;

    smp[t] = (t < b) ? bsum[t] : 0;
    int c = (i < N) ? counts[i] : 0;
    sm[t] = c;
    __syncthreads();
#pragma unroll
    for (int off = 128; off; off >>= 1) {
        if (t < off) smp[t] += smp[t + off];
        __syncthreads();
    }
    int prefix = smp[0];
    for (int off = 1; off < 256; off <<= 1) {
        int v = (t >= off) ? sm[t - off] : 0;
        __syncthreads();
        sm[t] += v;
        __syncthreads();
    }
    int ex = prefix + sm[t] - c;           // exclusive scan value
    if (i < N) { rowptr[i] = ex; cursor[i] = ex; }
    if (i == 0) rowptr[N] = E;
}

__global__ __launch_bounds__(256) void scatter_kernel(
    const int* __restrict__ src, const int* __restrict__ dst,
    const float* __restrict__ reward, int* __restrict__ cursor,
    u64_t* __restrict__ epair, int E) {
    int i = blockIdx.x * 256 + threadIdx.x;
    if (i < E) {
        int d = dst[i];
        int pos = atomicAdd(&cursor[d], 1);
        epair[pos] = ((u64_t)__float_as_uint(reward[i]) << 32) | (unsigned)src[i];
    }
}

// ---- fused per-node edge phase (r8-exact) -----------------------------------

__global__ __launch_bounds__(256) void node_fused(
    const ushort_t* __restrict__ fnih, const ushort_t* __restrict__ fnj,
    const int* __restrict__ rowptr, const u64_t* __restrict__ epair,
    const float* __restrict__ wsum, const float* __restrict__ attn,
    float* __restrict__ out, int N) {
    int node = (int)((blockIdx.x * (size_t)blockDim.x + threadIdx.x) >> 6);
    int lane = threadIdx.x & 63;
    if (node >= N) return;

    int base = rowptr[node], end = rowptr[node + 1];
    int j0 = lane * 4;
    if (base >= end) { out[(size_t)node * 64 + lane] = 0.f; return; }

    float4 ws = *(const float4*)(wsum + j0);
    float4 at = *(const float4*)(attn + j0);
    ushort4 njv = *(const ushort4*)(fnj + (size_t)node * 256 + j0);
    float nj0 = bf2f(njv.x), nj1 = bf2f(njv.y), nj2 = bf2f(njv.z), nj3 = bf2f(njv.w);

    float a0 = 0.f, a1 = 0.f, a2 = 0.f, a3 = 0.f, dsum = 0.f;
    const int lo16 = lane * 8;   // 16B chunk offset (shorts) within a fnih row

    u64_t p0 = epair[base];
    u64_t p1 = (base + 1 < end) ? epair[base + 1] : 0;
    int s0 = __builtin_amdgcn_readfirstlane((int)(unsigned)p0);
    uint4 gv = *(const uint4*)(fnih + (size_t)(unsigned)s0 * 512 + lo16);

    for (int e = base; e < end; ++e) {
        u64_t pn = (e + 2 < end) ? epair[e + 2] : 0;
        uint4 gv_n = gv;
        if (e + 1 < end) {
            int s1 = __builtin_amdgcn_readfirstlane((int)(unsigned)p1);
            gv_n = *(const uint4*)(fnih + (size_t)(unsigned)s1 * 512 + lo16);
        }

        float r = __uint_as_float(
            __builtin_amdgcn_readfirstlane((int)(unsigned)(p0 >> 32)));
        float2 b01 = bfx2(gv.x), b23 = bfx2(gv.y);
        float x0 = fmaf(r, ws.x, nj0) + b01.x;
        float x1 = fmaf(r, ws.y, nj1) + b01.y;
        float x2 = fmaf(r, ws.z, nj2) + b23.x;
        float x3 = fmaf(r, ws.w, nj3) + b23.y;
        x0 = fmaxf(x0, 0.2f * x0);
        x1 = fmaxf(x1, 0.2f * x1);
        x2 = fmaxf(x2, 0.2f * x2);
        x3 = fmaxf(x3, 0.2f * x3);
        float acc = at.x * x0 + at.y * x1 + at.z * x2 + at.w * x3;
        acc += __shfl_xor(acc, 1, 64);
        acc += __shfl_xor(acc, 2, 64);
        acc += __shfl_xor(acc, 4, 64);
        acc += __shfl_xor(acc, 8, 64);
        float eh = __expf(acc);
        dsum += eh;

        float e0 = __shfl(eh, 0, 64);
        float e1 = __shfl(eh, 16, 64);
        float e2 = __shfl(eh, 32, 64);
        float e3 = __shfl(eh, 48, 64);
        float2 h01 = bfx2(gv.z), h23 = bfx2(gv.w);
        a0 = fmaf(e0, h01.x, a0);
        a1 = fmaf(e1, h01.y, a1);
        a2 = fmaf(e2, h23.x, a2);
        a3 = fmaf(e3, h23.y, a3);

        p0 = p1; p1 = pn; gv = gv_n;
    }

    float d0 = __shfl(dsum, 0, 64);
    float d1 = __shfl(dsum, 16, 64);
    float d2 = __shfl(dsum, 32, 64);
    float d3 = __shfl(dsum, 48, 64);
    float v = 0.25f * (__fdividef(a0, d0) + __fdividef(a1, d1) +
                       __fdividef(a2, d2) + __fdividef(a3, d3));
    out[(size_t)node * 64 + lane] = fmaxf(v, 0.f);
}

// ---- launch -----------------------------------------------------------------

extern "C" void kernel_launch(void* const* d_in, const int* in_sizes, int n_in,
                              void* d_out, int out_size, void* d_ws, size_t ws_size,
                              hipStream_t stream) {
    const float* nfeats = (const float*)d_in[0];
    const float* reward = (const float*)d_in[1];
    const int* src = (const int*)d_in[2];
    const int* dst = (const int*)d_in[3];
    const float* Wni = (const float*)d_in[4];
    const float* Wnj = (const float*)d_in[5];
    const float* Wfij = (const float*)d_in[6];
    const float* Wnode = (const float*)d_in[7];
    const float* bias = (const float*)d_in[8];
    const float* attn = (const float*)d_in[9];
    float* out = (float*)d_out;

    const int N = in_sizes[0] / 256;
    const int E = in_sizes[1];
    const int NB = (N + 255) / 256;       // <= 256 (N <= 65536)
    const int total4 = N * 64;
    const int castB = (total4 + 1023) / 1024;
    const int countB = (E + 255) / 256;

    char* p = (char*)d_ws;
    auto alloc = [&](size_t bytes) { char* r = p; p += (bytes + 63) & ~63ull; return r; };
    u64_t* epair = (u64_t*)alloc((size_t)E * sizeof(u64_t));
    float* wsum = (float*)alloc(256 * sizeof(float));
    int* counts = (int*)alloc((size_t)N * sizeof(int));
    int* bsum = (int*)alloc(256 * sizeof(int));
    int* rowptr = (int*)alloc((size_t)(N + 1) * sizeof(int));
    int* cursor = (int*)alloc((size_t)N * sizeof(int));
    ushort_t* fnih = (ushort_t*)alloc((size_t)N * 512 * sizeof(ushort_t));
    ushort_t* fnj = (ushort_t*)alloc((size_t)N * 256 * sizeof(ushort_t));
    ushort_t* Abf = (ushort_t*)alloc((size_t)N * 256 * sizeof(ushort_t));
    ushort_t* BcatT = (ushort_t*)alloc((size_t)768 * 256 * sizeof(ushort_t));

    hipMemsetAsync(counts, 0, (size_t)N * sizeof(int), stream);

    prep_kernel<<<castB + 768 + countB + 1, 256, 0, stream>>>(
        nfeats, Wni, Wnj, Wnode, Wfij, dst, Abf, BcatT, wsum, counts,
        castB, countB, total4, E);

    scan_block_sums<<<NB, 256, 0, stream>>>(counts, bsum, N);
    scan_final<<<NB, 256, 0, stream>>>(counts, bsum, rowptr, cursor, N, E);
    scatter_kernel<<<countB, 256, 0, stream>>>(src, dst, reward, cursor, epair, E);

    dim3 g1((N + 127) / 128, 6);
    gemm_mfma<<<g1, 256, 0, stream>>>(Abf, BcatT, bias, fnih, fnj, N);

    node_fused<<<(N + 3) / 4, 256, 0, stream>>>(fnih, fnj, rowptr, epair,
                                                wsum, attn, out, N);
}

// Round 10
// 372.743 us; speedup vs baseline: 1.2608x; 1.0223x over previous
//
#include <hip/hip_runtime.h>

// EdgeGAT on MI355X — round 10: head-aligned node aggregation (no per-edge
// broadcasts) + scatter fused into the gemm dispatch.
//
//   memset counts; prep: cast | BcatT | wsum | dst hist
//   scan_block_sums + scan_final(self-prefix)
//   sg_fused: blocks [0, scatB) = edge scatter (overlaps gemm);
//             blocks [scatB, ..) = 128x128 dbuf global_load_lds GEMM.
//     fnih row layout (512 shorts, lane l = 16q+l16 reads uint4 at l*8):
//       slots 0..3: ni dims l*4..l*4+3  (head of these dims = q)
//       slots 4..7: hv[head=q][o = l16 + 16m], m=0..3   <-- NEW mapping
//   node_fused: per-edge: gather + logit + 4 xor-shfl + exp + 4 fma (eh is
//     lane-local for this head). Once per node: /dsum, cross-quad 2 shfl,
//     coalesced store.

typedef unsigned short ushort_t;
typedef __attribute__((ext_vector_type(8))) short frag_t;     // 8 bf16 (4 VGPRs)
typedef __attribute__((ext_vector_type(4))) float f32x4;
typedef unsigned long long u64_t;

__device__ __forceinline__ ushort_t f2bf(float f) {
    unsigned u = __float_as_uint(f);
    unsigned r = u + 0x7fffu + ((u >> 16) & 1u);   // round-to-nearest-even
    return (ushort_t)(r >> 16);
}
__device__ __forceinline__ float bf2f(ushort_t v) {
    return __uint_as_float(((unsigned)v) << 16);
}
__device__ __forceinline__ float2 bfx2(unsigned u) {   // packed [lo,hi] bf16 -> float2
    float2 f;
    f.x = __uint_as_float(u << 16);
    f.y = __uint_as_float(u & 0xffff0000u);
    return f;
}

// async 16B global->LDS
__device__ __forceinline__ void async_load16(const void* g, void* l) {
    __builtin_amdgcn_global_load_lds(
        (const __attribute__((address_space(1))) unsigned int*)g,
        (__attribute__((address_space(3))) unsigned int*)(unsigned int)(uintptr_t)l,
        16, 0, 0);
}

// ---- fused prep: cast | bcatT | wsum | count --------------------------------
__global__ __launch_bounds__(256) void prep_kernel(
    const float* __restrict__ nfeats, const float* __restrict__ Wni,
    const float* __restrict__ Wnj, const float* __restrict__ Wnode,
    const float* __restrict__ Wfij, const int* __restrict__ dst,
    ushort_t* __restrict__ Abf, ushort_t* __restrict__ BcatT,
    float* __restrict__ wsum, int* __restrict__ counts,
    int castB, int countB, int total4, int E) {
    int b = blockIdx.x;
    int t = threadIdx.x;
    if (b < castB) {                       // cast nfeats: 4x float4 per thread
#pragma unroll
        for (int cc = 0; cc < 4; ++cc) {
            int i = (b * 4 + cc) * 256 + t;
            if (i >= total4) break;
            float4 v = *(const float4*)(nfeats + (size_t)i * 4);
            ushort4 o;
            o.x = f2bf(v.x); o.y = f2bf(v.y); o.z = f2bf(v.z); o.w = f2bf(v.w);
            *(ushort4*)(Abf + (size_t)i * 4) = o;
        }
    } else if (b < castB + 768) {          // BcatT[j][k]
        int j = b - castB;
        int seg = j >> 8;
        const float* W = (seg == 0) ? Wni : (seg == 1) ? Wnj : Wnode;
        BcatT[(size_t)j * 256 + t] = f2bf(W[(size_t)t * 256 + (j & 255)]);
    } else if (b < castB + 768 + countB) { // dst histogram
        int i = (b - castB - 768) * 256 + t;
        if (i < E) atomicAdd(&counts[dst[i]], 1);
    } else {                               // wsum
        float s = 0.f;
#pragma unroll
        for (int k = 0; k < 32; ++k) s += Wfij[k * 256 + t];
        wsum[t] = s;
    }
}

// ---- scans ------------------------------------------------------------------

__global__ __launch_bounds__(256) void scan_block_sums(const int* __restrict__ counts,
                                                       int* __restrict__ bsum, int N) {
    __shared__ int sm[256];
    int i = blockIdx.x * 256 + threadIdx.x;
    sm[threadIdx.x] = (i < N) ? counts[i] : 0;
    __syncthreads();
#pragma unroll
    for (int off = 128; off; off >>= 1) {
        if (threadIdx.x < off) sm[threadIdx.x] += sm[threadIdx.x + off];
        __syncthreads();
    }
    if (threadIdx.x == 0) bsum[blockIdx.x] = sm[0];
}

__global__ __launch_bounds__(256) void scan_final(const int* __restrict__ counts,
                                                  const int* __restrict__ bsum,
                                                  int* __restrict__ rowptr,
                                                  int* __restrict__ cursor, int N, int E) {
    __shared__ int sm[256];
    __shared__ int smp[256];
    int t = threadIdx.x;
    int b = blockIdx.x;
    int i = b * 256 + t;

    smp[t] = (t < b) ? bsum[t] : 0;
    int c = (i < N) ? counts[i] : 0;
    sm[t] = c;
    __syncthreads();
#pragma unroll
    for (int off = 128; off; off >>= 1) {
        if (t < off) smp[t] += smp[t + off];
        __syncthreads();
    }
    int prefix = smp[0];
    for (int off = 1; off < 256; off <<= 1) {
        int v = (t >= off) ? sm[t - off] : 0;
        __syncthreads();
        sm[t] += v;
        __syncthreads();
    }
    int ex = prefix + sm[t] - c;
    if (i < N) { rowptr[i] = ex; cursor[i] = ex; }
    if (i == 0) rowptr[N] = E;
}

// ---- fused scatter + MFMA GEMM ----------------------------------------------
// blocks [0, scatB): edge scatter. blocks [scatB, scatB+gemmB): gemm, flattened
// (row-block = bx % gX, col-block = bx / gX).
__global__ __launch_bounds__(256) void sg_fused(
    // scatter args
    const int* __restrict__ src, const int* __restrict__ dst,
    const float* __restrict__ reward, int* __restrict__ cursor,
    u64_t* __restrict__ epair, int E, int scatB,
    // gemm args
    const ushort_t* __restrict__ A, const ushort_t* __restrict__ BT,
    const float* __restrict__ bias, ushort_t* __restrict__ fnih,
    ushort_t* __restrict__ fnj, int N, int gX) {
    __shared__ ushort_t As[2][128][32];
    __shared__ ushort_t Bs[2][128][32];

    if ((int)blockIdx.x < scatB) {
        int i = blockIdx.x * 256 + threadIdx.x;
        if (i < E) {
            int d = dst[i];
            int pos = atomicAdd(&cursor[d], 1);
            epair[pos] = ((u64_t)__float_as_uint(reward[i]) << 32) | (unsigned)src[i];
        }
        return;
    }

    const int bx = blockIdx.x - scatB;
    const int brow = bx % gX;
    const int bcol = bx / gX;

    const int tid = threadIdx.x;
    const int wave = tid >> 6, lane = tid & 63;
    const int quad = lane >> 4, l16 = lane & 15;
    const int wr = wave & 1, wc = wave >> 1;
    const int row0 = brow * 128;
    const int col0 = bcol * 128;               // 0..640
    const int Nm1 = N - 1;
    const int srow = lane >> 2;
    const int skof = (lane & 3) * 8;

    f32x4 acc[4][4] = {};

#pragma unroll
    for (int j = 0; j < 2; ++j) {
        int r = wave * 32 + j * 16 + srow;
        int grow = row0 + r; if (grow > Nm1) grow = Nm1;
        async_load16(A + (size_t)grow * 256 + skof, &As[0][wave * 32 + j * 16][0]);
        async_load16(BT + (size_t)(col0 + r) * 256 + skof, &Bs[0][wave * 32 + j * 16][0]);
    }

    for (int it = 0; it < 8; ++it) {
        const int cur = it & 1;
        __syncthreads();
        if (it < 7) {
            const int k1 = (it + 1) * 32;
#pragma unroll
            for (int j = 0; j < 2; ++j) {
                int r = wave * 32 + j * 16 + srow;
                int grow = row0 + r; if (grow > Nm1) grow = Nm1;
                async_load16(A + (size_t)grow * 256 + k1 + skof,
                             &As[1 - cur][wave * 32 + j * 16][0]);
                async_load16(BT + (size_t)(col0 + r) * 256 + k1 + skof,
                             &Bs[1 - cur][wave * 32 + j * 16][0]);
            }
        }

        frag_t af[4], bfr[4];
#pragma unroll
        for (int i = 0; i < 4; ++i)
            af[i] = *(const frag_t*)&As[cur][wr * 64 + i * 16 + l16][quad * 8];
#pragma unroll
        for (int j = 0; j < 4; ++j)
            bfr[j] = *(const frag_t*)&Bs[cur][wc * 64 + j * 16 + l16][quad * 8];

#pragma unroll
        for (int i = 0; i < 4; ++i)
#pragma unroll
            for (int j = 0; j < 4; ++j)
                acc[i][j] = __builtin_amdgcn_mfma_f32_16x16x32_bf16(af[i], bfr[j], acc[i][j], 0, 0, 0);
    }

    // epilogue: fnih interleaved row layout:
    //   ni dim c  -> offset (c>>2)*8 + (c&3)
    //   hv (h,o)  -> lane = h*16 + (o&15), slot = 4 + (o>>4)
#pragma unroll
    for (int i = 0; i < 4; ++i) {
#pragma unroll
        for (int j = 0; j < 4; ++j) {
#pragma unroll
            for (int r = 0; r < 4; ++r) {
                int row = row0 + wr * 64 + i * 16 + quad * 4 + r;
                if (row >= N) continue;
                int col = col0 + wc * 64 + j * 16 + l16;
                float v = acc[i][j][r];
                if (col < 256) {
                    fnih[(size_t)row * 512 + (col >> 2) * 8 + (col & 3)] =
                        f2bf(v + bias[col]);
                } else if (col < 512) {
                    fnj[(size_t)row * 256 + (col - 256)] = f2bf(v);
                } else {
                    int c2 = col - 512;   // h = c2>>6, o = c2&63
                    int h = c2 >> 6, o = c2 & 63;
                    fnih[(size_t)row * 512 + (h * 16 + (o & 15)) * 8 + 4 + (o >> 4)] =
                        f2bf(v);
                }
            }
        }
    }
}

// ---- fused per-node edge phase (head-aligned aggregation) -------------------

__global__ __launch_bounds__(256) void node_fused(
    const ushort_t* __restrict__ fnih, const ushort_t* __restrict__ fnj,
    const int* __restrict__ rowptr, const u64_t* __restrict__ epair,
    const float* __restrict__ wsum, const float* __restrict__ attn,
    float* __restrict__ out, int N) {
    int node = (int)((blockIdx.x * (size_t)blockDim.x + threadIdx.x) >> 6);
    int lane = threadIdx.x & 63;
    if (node >= N) return;

    int base = rowptr[node], end = rowptr[node + 1];
    int j0 = lane * 4;
    if (base >= end) { out[(size_t)node * 64 + lane] = 0.f; return; }

    float4 ws = *(const float4*)(wsum + j0);
    float4 at = *(const float4*)(attn + j0);
    ushort4 njv = *(const ushort4*)(fnj + (size_t)node * 256 + j0);
    float nj0 = bf2f(njv.x), nj1 = bf2f(njv.y), nj2 = bf2f(njv.z), nj3 = bf2f(njv.w);

    float a0 = 0.f, a1 = 0.f, a2 = 0.f, a3 = 0.f, dsum = 0.f;
    const int lo16 = lane * 8;   // 16B chunk offset (shorts) within a fnih row

    u64_t p0 = epair[base];
    u64_t p1 = (base + 1 < end) ? epair[base + 1] : 0;
    int s0 = __builtin_amdgcn_readfirstlane((int)(unsigned)p0);
    uint4 gv = *(const uint4*)(fnih + (size_t)(unsigned)s0 * 512 + lo16);

    for (int e = base; e < end; ++e) {
        u64_t pn = (e + 2 < end) ? epair[e + 2] : 0;
        uint4 gv_n = gv;
        if (e + 1 < end) {
            int s1 = __builtin_amdgcn_readfirstlane((int)(unsigned)p1);
            gv_n = *(const uint4*)(fnih + (size_t)(unsigned)s1 * 512 + lo16);
        }

        float r = __uint_as_float(
            __builtin_amdgcn_readfirstlane((int)(unsigned)(p0 >> 32)));
        float2 b01 = bfx2(gv.x), b23 = bfx2(gv.y);
        float x0 = fmaf(r, ws.x, nj0) + b01.x;
        float x1 = fmaf(r, ws.y, nj1) + b01.y;
        float x2 = fmaf(r, ws.z, nj2) + b23.x;
        float x3 = fmaf(r, ws.w, nj3) + b23.y;
        x0 = fmaxf(x0, 0.2f * x0);
        x1 = fmaxf(x1, 0.2f * x1);
        x2 = fmaxf(x2, 0.2f * x2);
        x3 = fmaxf(x3, 0.2f * x3);
        float acc = at.x * x0 + at.y * x1 + at.z * x2 + at.w * x3;
        acc += __shfl_xor(acc, 1, 64);
        acc += __shfl_xor(acc, 2, 64);
        acc += __shfl_xor(acc, 4, 64);
        acc += __shfl_xor(acc, 8, 64);
        float eh = __expf(acc);         // every lane: exp logit of head = quad
        dsum += eh;

        // hv slots are head-aligned: slot m = hv[head=quad][o = l16 + 16m]
        float2 h01 = bfx2(gv.z), h23 = bfx2(gv.w);
        a0 = fmaf(eh, h01.x, a0);
        a1 = fmaf(eh, h01.y, a1);
        a2 = fmaf(eh, h23.x, a2);
        a3 = fmaf(eh, h23.y, a3);

        p0 = p1; p1 = pn; gv = gv_n;
    }

    // normalize by this head's denom, then sum across quads (heads)
    float inv = __fdividef(0.25f, dsum);
    float v0 = a0 * inv, v1 = a1 * inv, v2 = a2 * inv, v3 = a3 * inv;
    v0 += __shfl_xor(v0, 16, 64); v1 += __shfl_xor(v1, 16, 64);
    v2 += __shfl_xor(v2, 16, 64); v3 += __shfl_xor(v3, 16, 64);
    v0 += __shfl_xor(v0, 32, 64); v1 += __shfl_xor(v1, 32, 64);
    v2 += __shfl_xor(v2, 32, 64); v3 += __shfl_xor(v3, 32, 64);
    // lane writes o = lane: select m = quad (o = l16 + 16*quad)
    int quad = lane >> 4;
    float v = (quad == 0) ? v0 : (quad == 1) ? v1 : (quad == 2) ? v2 : v3;
    out[(size_t)node * 64 + lane] = fmaxf(v, 0.f);
}

// ---- launch -----------------------------------------------------------------

extern "C" void kernel_launch(void* const* d_in, const int* in_sizes, int n_in,
                              void* d_out, int out_size, void* d_ws, size_t ws_size,
                              hipStream_t stream) {
    const float* nfeats = (const float*)d_in[0];
    const float* reward = (const float*)d_in[1];
    const int* src = (const int*)d_in[2];
    const int* dst = (const int*)d_in[3];
    const float* Wni = (const float*)d_in[4];
    const float* Wnj = (const float*)d_in[5];
    const float* Wfij = (const float*)d_in[6];
    const float* Wnode = (const float*)d_in[7];
    const float* bias = (const float*)d_in[8];
    const float* attn = (const float*)d_in[9];
    float* out = (float*)d_out;

    const int N = in_sizes[0] / 256;
    const int E = in_sizes[1];
    const int NB = (N + 255) / 256;       // <= 256 (N <= 65536)
    const int total4 = N * 64;
    const int castB = (total4 + 1023) / 1024;
    const int countB = (E + 255) / 256;

    char* p = (char*)d_ws;
    auto alloc = [&](size_t bytes) { char* r = p; p += (bytes + 63) & ~63ull; return r; };
    u64_t* epair = (u64_t*)alloc((size_t)E * sizeof(u64_t));
    float* wsum = (float*)alloc(256 * sizeof(float));
    int* counts = (int*)alloc((size_t)N * sizeof(int));
    int* bsum = (int*)alloc(256 * sizeof(int));
    int* rowptr = (int*)alloc((size_t)(N + 1) * sizeof(int));
    int* cursor = (int*)alloc((size_t)N * sizeof(int));
    ushort_t* fnih = (ushort_t*)alloc((size_t)N * 512 * sizeof(ushort_t));
    ushort_t* fnj = (ushort_t*)alloc((size_t)N * 256 * sizeof(ushort_t));
    ushort_t* Abf = (ushort_t*)alloc((size_t)N * 256 * sizeof(ushort_t));
    ushort_t* BcatT = (ushort_t*)alloc((size_t)768 * 256 * sizeof(ushort_t));

    hipMemsetAsync(counts, 0, (size_t)N * sizeof(int), stream);

    prep_kernel<<<castB + 768 + countB + 1, 256, 0, stream>>>(
        nfeats, Wni, Wnj, Wnode, Wfij, dst, Abf, BcatT, wsum, counts,
        castB, countB, total4, E);

    scan_block_sums<<<NB, 256, 0, stream>>>(counts, bsum, N);
    scan_final<<<NB, 256, 0, stream>>>(counts, bsum, rowptr, cursor, N, E);

    const int gX = (N + 127) / 128;
    const int gemmB = gX * 6;
    sg_fused<<<countB + gemmB, 256, 0, stream>>>(
        src, dst, reward, cursor, epair, E, countB,
        Abf, BcatT, bias, fnih, fnj, N, gX);

    node_fused<<<(N + 3) / 4, 256, 0, stream>>>(fnih, fnj, rowptr, epair,
                                                wsum, attn, out, N);
}